// Round 2
// baseline (770.344 us; speedup 1.0000x reference)
//
#include <hip/hip_runtime.h>
#include <stdint.h>

// InnerMonologue: PR = hid @ W_to + b_to ; proj = PR @ W_from + b_from
// out = mask ? proj : hid ; mask = parity of cumulative thought-token count (row 0).
// Outputs concat: PR (B,S,P) | out (B,S,H) | is_private (B,S) | usage (B), all fp32.
//
// R2: both GEMMs -> double-buffered LDS, ONE raw s_barrier per K-step (no vmcnt
// drain), depth-2 register prefetch (issue t+2 before consuming t+1). K-step 32,
// padded-40 LDS rows (2-way = free). Native __bf16 casts in staging. prep kernel
// merges mask + both weight transposes.

#define H 2048
#define P 256
#define BB 4
#define S 8192
#define M_TOTAL (BB * S)

typedef __bf16 bf16_t;
typedef __bf16 bf16x4 __attribute__((ext_vector_type(4)));
typedef __bf16 bf16x8 __attribute__((ext_vector_type(8)));
typedef float f32x4 __attribute__((ext_vector_type(4)));

__device__ __forceinline__ ushort f2b(float f) {
  // fp32 -> bf16 round-to-nearest-even (prep kernel only)
  uint32_t u = __float_as_uint(f);
  u += 0x7fffu + ((u >> 16) & 1u);
  return (ushort)(u >> 16);
}

// Raw barrier: ds-writes made visible (lgkmcnt 0) but global loads stay in
// flight across the barrier (no vmcnt drain -> prefetch survives).
__device__ __forceinline__ void pipe_barrier() {
  asm volatile("s_waitcnt lgkmcnt(0)" ::: "memory");
  __builtin_amdgcn_s_barrier();
  asm volatile("" ::: "memory");
}

// ---------------- prep: both weight transposes + mask, one launch ----------------
// blocks 0..511: W_to (H x P) -> wtT (P x H) bf16 ; 512..1023: W_from -> wfT ;
// block 1024: mask / is_private / usage.
__global__ __launch_bounds__(256) void prep(
    const float* __restrict__ W_to, const float* __restrict__ W_from,
    ushort* __restrict__ wtT, ushort* __restrict__ wfT,
    const int* __restrict__ tok, const int* __restrict__ tt_p,
    float* __restrict__ maskf, float* __restrict__ out2, float* __restrict__ out3) {
  __shared__ float tile[32][33];
  __shared__ unsigned long long wpar[4];
  __shared__ int wcnt[4];
  const int b = blockIdx.x;
  const int t = threadIdx.x;
  if (b < 1024) {
    const float* in = (b < 512) ? W_to : W_from;
    ushort* out = (b < 512) ? wtT : wfT;
    const int R = (b < 512) ? H : P;
    const int C = (b < 512) ? P : H;
    const int bb = b & 511;
    const int nct = C >> 5;
    const int c0 = (bb % nct) * 32, r0 = (bb / nct) * 32;
    const int tx = t & 31, ty = t >> 5;  // 32 x 8
#pragma unroll
    for (int j = 0; j < 32; j += 8)
      tile[ty + j][tx] = in[(size_t)(r0 + ty + j) * C + c0 + tx];
    __syncthreads();
#pragma unroll
    for (int j = 0; j < 32; j += 8)
      out[(size_t)(c0 + ty + j) * R + r0 + tx] = f2b(tile[tx][ty + j]);
  } else {
    const int lane = t & 63, w = t >> 6;
    const int tt = tt_p[0];
    const int base = t * 32;
    unsigned bits = 0;
    for (int i = 0; i < 32; i++) bits |= (unsigned)(tok[base + i] == tt) << i;
    const int par = __popc(bits) & 1;
    const unsigned long long bal = __ballot(par != 0);
    if (lane == 0) wpar[w] = bal;
    __syncthreads();
    int pre = 0;
    for (int j = 0; j < w; j++) pre ^= (int)(__popcll(wpar[j]) & 1);
    pre ^= (int)(__popcll(bal & ((1ull << lane) - 1ull)) & 1);
    int cnt = 0;
    for (int i = 0; i < 32; i++) {
      int inc = __popc(bits << (31 - i)) & 1;  // inclusive parity of bits[0..i]
      int bit = pre ^ inc;
      cnt += bit;
      float fb = (float)bit;
      maskf[base + i] = fb;
      out2[0 * S + base + i] = fb;
      out2[1 * S + base + i] = fb;
      out2[2 * S + base + i] = fb;
      out2[3 * S + base + i] = fb;
    }
    for (int off = 32; off; off >>= 1) cnt += __shfl_down(cnt, off);
    if (lane == 0) wcnt[w] = cnt;
    __syncthreads();
    if (t < BB) {
      int tot = wcnt[0] + wcnt[1] + wcnt[2] + wcnt[3];
      out3[t] = (float)tot / (float)S;
    }
  }
}

// ---------------- GEMM1: PR(64x256 per block) = hid @ W_to + b_to ----------------
// grid 512 x 512 thr. K-step 32, dbuf LDS 50KB, 1 raw barrier/step, depth-2 reg
// prefetch. 8 waves each own 64 rows x 32 cols (acc[4][2]).
__global__ __launch_bounds__(512) void gemm1(
    const float* __restrict__ hid,
    const ushort* __restrict__ wtT,   // P x H bf16  (W_to^T)
    const float* __restrict__ b_to,
    float* __restrict__ out0)         // (B*S, P) fp32
{
  __shared__ bf16_t sA[2][64 * 40];
  __shared__ bf16_t sW[2][256 * 40];
  const int tid = threadIdx.x;
  const int lane = tid & 63, wid = tid >> 6;
  const int quad = lane >> 4, l16 = lane & 15;
  const int row0 = blockIdx.x * 64;

  const int ar = tid >> 3, ac = tid & 7;  // A stage: row 0..63, chunk of 4 fp32
  const int wn = tid >> 2, ws = tid & 3;  // W stage: rows wn, wn+128; chunk of 8 bf16

  const float* aSrc = hid + (size_t)(row0 + ar) * H + ac * 4;
  const ushort* wSrc0 = wtT + (size_t)wn * H + ws * 8;
  const ushort* wSrc1 = wtT + (size_t)(wn + 128) * H + ws * 8;

  float4 pA[2];
  int4 pW[2][2];

  f32x4 acc[4][2];
  const f32x4 zero = {0.f, 0.f, 0.f, 0.f};
#pragma unroll
  for (int i = 0; i < 4; i++)
#pragma unroll
    for (int j = 0; j < 2; j++) acc[i][j] = zero;

#define G1_ISSUE(s, k0)                          \
  do {                                           \
    pA[s] = *(const float4*)(aSrc + (k0));       \
    pW[s][0] = *(const int4*)(wSrc0 + (k0));     \
    pW[s][1] = *(const int4*)(wSrc1 + (k0));     \
  } while (0)

#define G1_WRITE(s, bf)                                      \
  do {                                                       \
    bf16x4 cv;                                               \
    cv.x = (bf16_t)pA[s].x; cv.y = (bf16_t)pA[s].y;          \
    cv.z = (bf16_t)pA[s].z; cv.w = (bf16_t)pA[s].w;          \
    *(bf16x4*)(&sA[bf][ar * 40 + ac * 4]) = cv;              \
    *(int4*)(&sW[bf][wn * 40 + ws * 8]) = pW[s][0];          \
    *(int4*)(&sW[bf][(wn + 128) * 40 + ws * 8]) = pW[s][1];  \
  } while (0)

#define G1_COMPUTE(bf)                                                            \
  do {                                                                            \
    bf16x8 af[4], bw[2];                                                          \
    _Pragma("unroll") for (int i = 0; i < 4; ++i)                                 \
        af[i] = *(const bf16x8*)(&sA[bf][(i * 16 + l16) * 40 + quad * 8]);        \
    _Pragma("unroll") for (int j = 0; j < 2; ++j)                                 \
        bw[j] = *(const bf16x8*)(&sW[bf][(wid * 32 + j * 16 + l16) * 40 + quad * 8]); \
    _Pragma("unroll") for (int i = 0; i < 4; ++i)                                 \
        _Pragma("unroll") for (int j = 0; j < 2; ++j)                             \
            acc[i][j] = __builtin_amdgcn_mfma_f32_16x16x32_bf16(af[i], bw[j], acc[i][j], 0, 0, 0); \
  } while (0)

  // prologue: tiles 0 (set0) and 1 (set1) in flight; tile 0 -> buf0
  G1_ISSUE(0, 0);
  G1_ISSUE(1, 32);
  G1_WRITE(0, 0);
  pipe_barrier();

#pragma unroll 1
  for (int m = 0; m < 31; ++m) {
    const int k0 = 64 + (m << 6);
    G1_COMPUTE(0);          // tile 2m
    G1_ISSUE(0, k0);        // tile 2m+2
    G1_WRITE(1, 1);         // tile 2m+1 (waits its loads)
    pipe_barrier();
    G1_COMPUTE(1);          // tile 2m+1
    G1_ISSUE(1, k0 + 32);   // tile 2m+3
    G1_WRITE(0, 0);         // tile 2m+2
    pipe_barrier();
  }
  G1_COMPUTE(0);  // tile 62
  G1_WRITE(1, 1); // tile 63
  pipe_barrier();
  G1_COMPUTE(1);  // tile 63

  // epilogue: +b_to, write PR fp32
#pragma unroll
  for (int i = 0; i < 4; i++) {
#pragma unroll
    for (int j = 0; j < 2; j++) {
      int col = wid * 32 + j * 16 + l16;
      float bias = b_to[col];
#pragma unroll
      for (int e = 0; e < 4; e++) {
        int row = i * 16 + quad * 4 + e;
        out0[(size_t)(row0 + row) * P + col] = acc[i][j][e] + bias;
      }
    }
  }
#undef G1_ISSUE
#undef G1_WRITE
#undef G1_COMPUTE
}

// ---------------- GEMM2: out(128x128 per block) = blend(PR @ W_from + b_from) ----------------
// grid 4096 x 512 thr. K-step 32 (8 steps), dbuf LDS 40KB -> 4 blocks/CU eligible.
// Same pipeline. 8 waves as 4x2: each 32 rows x 64 cols (acc[2][4]).
// XCD swizzle keeps the 16 N-blocks sharing a PR panel on one XCD's L2.
__global__ __launch_bounds__(512) void gemm2(
    const float* __restrict__ pr,     // out0: (B*S, P) fp32
    const ushort* __restrict__ wfT,   // H x P bf16  (W_from^T)
    const float* __restrict__ b_from,
    const float* __restrict__ maskf,
    const float* __restrict__ hid,
    float* __restrict__ out1)         // (B*S, H) fp32
{
  __shared__ bf16_t sA[2][128 * 40];
  __shared__ bf16_t sW[2][128 * 40];
  const int tid = threadIdx.x;
  const int lane = tid & 63, wid = tid >> 6;
  const int quad = lane >> 4, l16 = lane & 15;

  const int u0 = ((blockIdx.x & 7) << 9) + (blockIdx.x >> 3);  // bijective (4096 % 8 == 0)
  const int row0 = (u0 >> 4) * 128, nc0 = (u0 & 15) * 128;
  const int wr = wid >> 1, wc = wid & 1;

  const int ar = tid >> 3, ac = tid & 7;  // A stage: rows ar, ar+64; chunk of 4 fp32
  const int wn = tid >> 2, ws = tid & 3;  // W stage: row wn; chunk of 8 bf16

  const float* aSrc0 = pr + (size_t)(row0 + ar) * P + ac * 4;
  const float* aSrc1 = pr + (size_t)(row0 + ar + 64) * P + ac * 4;
  const ushort* wSrc = wfT + (size_t)(nc0 + wn) * P + ws * 8;

  float4 pA[2][2];
  int4 pW[2];

  f32x4 acc[2][4];
  const f32x4 zero = {0.f, 0.f, 0.f, 0.f};
#pragma unroll
  for (int i = 0; i < 2; i++)
#pragma unroll
    for (int j = 0; j < 4; j++) acc[i][j] = zero;

#define G2_ISSUE(s, k0)                         \
  do {                                          \
    pA[s][0] = *(const float4*)(aSrc0 + (k0));  \
    pA[s][1] = *(const float4*)(aSrc1 + (k0));  \
    pW[s] = *(const int4*)(wSrc + (k0));        \
  } while (0)

#define G2_WRITE(s, bf)                                          \
  do {                                                           \
    bf16x4 c0_, c1_;                                             \
    c0_.x = (bf16_t)pA[s][0].x; c0_.y = (bf16_t)pA[s][0].y;      \
    c0_.z = (bf16_t)pA[s][0].z; c0_.w = (bf16_t)pA[s][0].w;      \
    c1_.x = (bf16_t)pA[s][1].x; c1_.y = (bf16_t)pA[s][1].y;      \
    c1_.z = (bf16_t)pA[s][1].z; c1_.w = (bf16_t)pA[s][1].w;      \
    *(bf16x4*)(&sA[bf][ar * 40 + ac * 4]) = c0_;                 \
    *(bf16x4*)(&sA[bf][(ar + 64) * 40 + ac * 4]) = c1_;          \
    *(int4*)(&sW[bf][wn * 40 + ws * 8]) = pW[s];                 \
  } while (0)

#define G2_COMPUTE(bf)                                                            \
  do {                                                                            \
    bf16x8 af[2], bw[4];                                                          \
    _Pragma("unroll") for (int i = 0; i < 2; ++i)                                 \
        af[i] = *(const bf16x8*)(&sA[bf][(wr * 32 + i * 16 + l16) * 40 + quad * 8]); \
    _Pragma("unroll") for (int j = 0; j < 4; ++j)                                 \
        bw[j] = *(const bf16x8*)(&sW[bf][(wc * 64 + j * 16 + l16) * 40 + quad * 8]); \
    _Pragma("unroll") for (int i = 0; i < 2; ++i)                                 \
        _Pragma("unroll") for (int j = 0; j < 4; ++j)                             \
            acc[i][j] = __builtin_amdgcn_mfma_f32_16x16x32_bf16(af[i], bw[j], acc[i][j], 0, 0, 0); \
  } while (0)

  G2_ISSUE(0, 0);
  G2_ISSUE(1, 32);
  G2_WRITE(0, 0);
  pipe_barrier();

#pragma unroll 1
  for (int m = 0; m < 3; ++m) {
    const int k0 = 64 + (m << 6);
    G2_COMPUTE(0);          // tile 2m
    G2_ISSUE(0, k0);        // tile 2m+2
    G2_WRITE(1, 1);         // tile 2m+1
    pipe_barrier();
    G2_COMPUTE(1);          // tile 2m+1
    G2_ISSUE(1, k0 + 32);   // tile 2m+3
    G2_WRITE(0, 0);         // tile 2m+2
    pipe_barrier();
  }
  G2_COMPUTE(0);  // tile 6
  G2_WRITE(1, 1); // tile 7
  pipe_barrier();
  G2_COMPUTE(1);  // tile 7

  // epilogue: +b_from, blend with hid (row-granular mask), store
#pragma unroll
  for (int i = 0; i < 2; i++) {
#pragma unroll
    for (int e = 0; e < 4; e++) {
      int row = wr * 32 + i * 16 + quad * 4 + e;
      size_t gr = (size_t)(row0 + row);
      float m = maskf[gr & (S - 1)];
      if (m != 0.0f) {
#pragma unroll
        for (int j = 0; j < 4; j++) {
          int col = nc0 + wc * 64 + j * 16 + l16;
          out1[gr * H + col] = acc[i][j][e] + b_from[col];
        }
      } else {
#pragma unroll
        for (int j = 0; j < 4; j++) {
          int col = nc0 + wc * 64 + j * 16 + l16;
          out1[gr * H + col] = hid[gr * H + col];
        }
      }
    }
  }
#undef G2_ISSUE
#undef G2_WRITE
#undef G2_COMPUTE
}

extern "C" void kernel_launch(void* const* d_in, const int* in_sizes, int n_in,
                              void* d_out, int out_size, void* d_ws, size_t ws_size,
                              hipStream_t stream) {
  const float* hid    = (const float*)d_in[0];
  const float* W_to   = (const float*)d_in[1];
  const float* b_to   = (const float*)d_in[2];
  const float* W_from = (const float*)d_in[3];
  const float* b_from = (const float*)d_in[4];
  const int*   tok    = (const int*)d_in[5];
  const int*   tt     = (const int*)d_in[6];

  // workspace: W_to^T bf16 (P*H) | W_from^T bf16 (H*P) | mask float (S)  ~2.1MB
  ushort* wtT = (ushort*)d_ws;
  ushort* wfT = wtT + (size_t)P * H;
  float* maskf = (float*)(wfT + (size_t)H * P);

  float* out0 = (float*)d_out;                    // private_reasoning (B,S,P)
  float* out1 = out0 + (size_t)BB * S * P;        // output (B,S,H)
  float* out2 = out1 + (size_t)BB * S * H;        // is_private (B,S)
  float* out3 = out2 + (size_t)BB * S;            // subspace_usage (B)

  hipLaunchKernelGGL(prep, dim3(1025), dim3(256), 0, stream,
                     W_to, W_from, wtT, wfT, tok, tt, maskf, out2, out3);
  hipLaunchKernelGGL(gemm1, dim3(M_TOTAL / 64), dim3(512), 0, stream, hid, wtT, b_to, out0);
  hipLaunchKernelGGL(gemm2, dim3((M_TOTAL / 128) * (H / 128)), dim3(512), 0, stream,
                     out0, wfT, b_from, maskf, hid, out1);
}

// Round 3
// 604.600 us; speedup vs baseline: 1.2741x; 1.2741x over previous
//
#include <hip/hip_runtime.h>
#include <stdint.h>

// InnerMonologue: PR = hid @ W_to + b_to ; proj = PR @ W_from + b_from
// out = mask ? proj : hid ; mask = parity of cumulative thought-token count (row 0).
// Outputs concat: PR (B,S,P) | out (B,S,H) | is_private (B,S) | usage (B), all fp32.
//
// R3: revert to R1's proven 2-barrier GEMM structure (R2's hand pipeline regressed,
// cf. m196/m141). Structural traffic cut instead:
//  - gemm1 writes out1 passthrough for unmasked rows from its staging registers.
//  - gemm2 computes ONLY masked rows via a compacted sorted row list (prep),
//    gathering PR rows and scattering out1. No hid re-read, no mask branch.

#define H 2048
#define P 256
#define BB 4
#define S 8192
#define M_TOTAL (BB * S)

typedef __bf16 bf16x8 __attribute__((ext_vector_type(8)));
typedef float f32x4 __attribute__((ext_vector_type(4)));

__device__ __forceinline__ ushort f2b(float f) {
  // fp32 -> bf16 round-to-nearest-even
  uint32_t u = __float_as_uint(f);
  u += 0x7fffu + ((u >> 16) & 1u);
  return (ushort)(u >> 16);
}

// ---------------- prep: weight transposes + mask + masked-row compaction ----------------
// blocks 0..511: W_to (H x P) -> wtT (P x H) ; 512..1023: W_from -> wfT ;
// block 1024: mask / is_private / usage / sorted masked-position list.
__global__ __launch_bounds__(256) void prep(
    const float* __restrict__ W_to, const float* __restrict__ W_from,
    ushort* __restrict__ wtT, ushort* __restrict__ wfT,
    const int* __restrict__ tok, const int* __restrict__ tt_p,
    float* __restrict__ maskf, int* __restrict__ slist, int* __restrict__ cntp,
    float* __restrict__ out2, float* __restrict__ out3) {
  __shared__ float tile[32][33];
  __shared__ unsigned long long wpar[4];
  __shared__ int scnt[256];
  const int b = blockIdx.x;
  const int t = threadIdx.x;
  if (b < 1024) {
    const float* in = (b < 512) ? W_to : W_from;
    ushort* out = (b < 512) ? wtT : wfT;
    const int R = (b < 512) ? H : P;
    const int C = (b < 512) ? P : H;
    const int bb = b & 511;
    const int nct = C >> 5;
    const int c0 = (bb % nct) * 32, r0 = (bb / nct) * 32;
    const int tx = t & 31, ty = t >> 5;  // 32 x 8
#pragma unroll
    for (int j = 0; j < 32; j += 8)
      tile[ty + j][tx] = in[(size_t)(r0 + ty + j) * C + c0 + tx];
    __syncthreads();
#pragma unroll
    for (int j = 0; j < 32; j += 8)
      out[(size_t)(c0 + ty + j) * R + r0 + tx] = f2b(tile[tx][ty + j]);
  } else {
    const int lane = t & 63, w = t >> 6;
    const int tt = tt_p[0];
    const int base = t * 32;
    unsigned bits = 0;
    for (int i = 0; i < 32; i++) bits |= (unsigned)(tok[base + i] == tt) << i;
    const int par = __popc(bits) & 1;
    const unsigned long long bal = __ballot(par != 0);
    if (lane == 0) wpar[w] = bal;
    __syncthreads();
    int pre = 0;
    for (int j = 0; j < w; j++) pre ^= (int)(__popcll(wpar[j]) & 1);
    pre ^= (int)(__popcll(bal & ((1ull << lane) - 1ull)) & 1);
    int cnt = 0;
    for (int i = 0; i < 32; i++) {
      int inc = __popc(bits << (31 - i)) & 1;  // inclusive parity of bits[0..i]
      cnt += pre ^ inc;
    }
    scnt[t] = cnt;
    __syncthreads();
    int off = 0, tot = 0;
    for (int j = 0; j < 256; j++) {
      if (j < t) off += scnt[j];
      tot += scnt[j];
    }
    for (int i = 0; i < 32; i++) {
      int inc = __popc(bits << (31 - i)) & 1;
      int bit = pre ^ inc;
      float fb = (float)bit;
      maskf[base + i] = fb;
      out2[0 * S + base + i] = fb;
      out2[1 * S + base + i] = fb;
      out2[2 * S + base + i] = fb;
      out2[3 * S + base + i] = fb;
      if (bit) slist[off++] = base + i;
    }
    const int padded = (tot + 127) & ~127;
    for (int idx = tot + t; idx < padded; idx += 256) slist[idx] = -1;
    if (t == 0) cntp[0] = tot;
    if (t < BB) out3[t] = (float)tot / (float)S;
  }
}

// ---------------- GEMM1: PR(64x256 per block) = hid @ W_to + b_to ----------------
// grid 512 x 512 threads. LDS = 64x72 + 256x72 ushort = 46KB -> 3 blocks/CU.
// 8 waves each own 64 rows x 32 cols (acc[4][2]).
// Passthrough: unmasked rows' hid float4 (already in staging regs) -> out1.
__global__ __launch_bounds__(512) void gemm1(
    const float* __restrict__ hid,
    const ushort* __restrict__ wtT,   // P x H bf16  (W_to^T)
    const float* __restrict__ b_to,
    const float* __restrict__ maskf,
    float* __restrict__ out0,         // (B*S, P) fp32
    float* __restrict__ out1)         // (B*S, H) fp32
{
  __shared__ ushort sA[64 * 72];
  __shared__ ushort sW[256 * 72];
  const int tid = threadIdx.x;
  const int lane = tid & 63, wid = tid >> 6;
  const int quad = lane >> 4, l16 = lane & 15;
  const int row0 = blockIdx.x * 64;

  // staging geometry: thread handles rows ra and ra+32, float4 chunk cc
  const int ra = tid >> 4, cc = tid & 15;
  const bool pass0 = (maskf[(row0 + ra) & (S - 1)] == 0.0f);
  const bool pass1 = (maskf[(row0 + 32 + ra) & (S - 1)] == 0.0f);
  const float* aSrc0 = hid + (size_t)(row0 + ra) * H + cc * 4;
  const float* aSrc1 = hid + (size_t)(row0 + 32 + ra) * H + cc * 4;
  float* pDst0 = out1 + (size_t)(row0 + ra) * H + cc * 4;
  float* pDst1 = out1 + (size_t)(row0 + 32 + ra) * H + cc * 4;

  f32x4 acc[4][2];
  const f32x4 zero = {0.f, 0.f, 0.f, 0.f};
#pragma unroll
  for (int i = 0; i < 4; i++)
#pragma unroll
    for (int j = 0; j < 2; j++) acc[i][j] = zero;

  for (int k0 = 0; k0 < H; k0 += 64) {
    // stage A: 64 rows x 64 k, fp32 -> bf16 ; passthrough unmasked rows to out1
    {
      const float4 v0 = *(const float4*)(aSrc0 + k0);
      ushort4 b0;
      b0.x = f2b(v0.x); b0.y = f2b(v0.y); b0.z = f2b(v0.z); b0.w = f2b(v0.w);
      *(ushort4*)(sA + ra * 72 + cc * 4) = b0;
      if (pass0) *(float4*)(pDst0 + k0) = v0;
      const float4 v1 = *(const float4*)(aSrc1 + k0);
      ushort4 b1;
      b1.x = f2b(v1.x); b1.y = f2b(v1.y); b1.z = f2b(v1.z); b1.w = f2b(v1.w);
      *(ushort4*)(sA + (32 + ra) * 72 + cc * 4) = b1;
      if (pass1) *(float4*)(pDst1 + k0) = v1;
    }
    // stage W_to^T: 256 n-rows x 64 k (bf16 copy, 2048 int4 units / 512 thr)
#pragma unroll
    for (int p = 0; p < 4; p++) {
      int u = p * 512 + tid;
      int n = u >> 3, s = u & 7;
      *(int4*)(sW + n * 72 + s * 8) = *(const int4*)(wtT + (size_t)n * H + k0 + s * 8);
    }
    __syncthreads();
#pragma unroll
    for (int kk = 0; kk < 64; kk += 32) {
      bf16x8 af[4], bfr[2];
#pragma unroll
      for (int t = 0; t < 4; t++)
        af[t] = *(const bf16x8*)(sA + (t * 16 + l16) * 72 + kk + quad * 8);
#pragma unroll
      for (int t = 0; t < 2; t++)
        bfr[t] = *(const bf16x8*)(sW + (wid * 32 + t * 16 + l16) * 72 + kk + quad * 8);
#pragma unroll
      for (int i = 0; i < 4; i++)
#pragma unroll
        for (int j = 0; j < 2; j++)
          acc[i][j] = __builtin_amdgcn_mfma_f32_16x16x32_bf16(af[i], bfr[j], acc[i][j], 0, 0, 0);
    }
    __syncthreads();
  }

  // epilogue: +b_to, write PR fp32 (all rows)
#pragma unroll
  for (int i = 0; i < 4; i++) {
#pragma unroll
    for (int j = 0; j < 2; j++) {
      int col = wid * 32 + j * 16 + l16;
      float bias = b_to[col];
#pragma unroll
      for (int e = 0; e < 4; e++) {
        int row = i * 16 + quad * 4 + e;
        out0[(size_t)(row0 + row) * P + col] = acc[i][j][e] + bias;
      }
    }
  }
}

// ---------------- GEMM2: masked rows only ----------------
// out1[masked] = PR[masked] @ W_from + b_from. 128 gathered rows x 128 cols per
// block; grid 4096, blocks beyond the active tile count exit immediately.
// slist is sorted -> gathered rows are nearly contiguous (coalescing preserved).
__global__ __launch_bounds__(512) void gemm2(
    const float* __restrict__ pr,     // out0: (B*S, P) fp32
    const ushort* __restrict__ wfT,   // H x P bf16  (W_from^T)
    const float* __restrict__ b_from,
    const int* __restrict__ slist,
    const int* __restrict__ cntp,
    float* __restrict__ out1)         // (B*S, H) fp32
{
  __shared__ ushort sA[128 * 72];
  __shared__ ushort sW[128 * 72];
  __shared__ int sIdx[128];
  const int tid = threadIdx.x;

  const int cnt = cntp[0];
  const int tpb = (cnt + 127) >> 7;   // m-tiles per batch
  const int u0 = ((blockIdx.x & 7) << 9) + (blockIdx.x >> 3);  // bijective XCD swizzle
  const int mt = u0 >> 4;
  if (mt >= 4 * tpb) return;
  const int nt = u0 & 15;
  const int batch = mt / tpb, ms = mt - batch * tpb;
  const int nc0 = nt * 128;
  const size_t rbase = (size_t)batch * S;

  if (tid < 128) sIdx[tid] = slist[ms * 128 + tid];
  __syncthreads();

  const int lane = tid & 63, wid = tid >> 6;
  const int quad = lane >> 4, l16 = lane & 15;
  const int wr = wid >> 1, wc = wid & 1;

  // staging geometry: thread handles tile rows ra + p*32, float4 chunk cc
  const int ra = tid >> 4, cc = tid & 15;
  const float* aSrc[4];
#pragma unroll
  for (int p = 0; p < 4; p++) {
    int sr = sIdx[ra + p * 32];
    int s = (sr < 0) ? 0 : sr;        // sentinel rows load row 0 (never stored)
    aSrc[p] = pr + (rbase + s) * P + cc * 4;
  }

  f32x4 acc[2][4];
  const f32x4 zero = {0.f, 0.f, 0.f, 0.f};
#pragma unroll
  for (int i = 0; i < 2; i++)
#pragma unroll
    for (int j = 0; j < 4; j++) acc[i][j] = zero;

  for (int k0 = 0; k0 < P; k0 += 64) {
    // stage A: 128 gathered rows x 64 k from PR fp32 -> bf16
#pragma unroll
    for (int p = 0; p < 4; p++) {
      const float4 v = *(const float4*)(aSrc[p] + k0);
      ushort4 b;
      b.x = f2b(v.x); b.y = f2b(v.y); b.z = f2b(v.z); b.w = f2b(v.w);
      *(ushort4*)(sA + (p * 32 + ra) * 72 + cc * 4) = b;
    }
    // stage W_from^T chunk: 128 n-rows x 64 k (1024 int4 / 512 thr)
#pragma unroll
    for (int p = 0; p < 2; p++) {
      int u = p * 512 + tid;
      int n = u >> 3, s = u & 7;
      *(int4*)(sW + n * 72 + s * 8) = *(const int4*)(wfT + (size_t)(nc0 + n) * P + k0 + s * 8);
    }
    __syncthreads();
#pragma unroll
    for (int kk = 0; kk < 64; kk += 32) {
      bf16x8 af[2], bfr[4];
#pragma unroll
      for (int t = 0; t < 2; t++)
        af[t] = *(const bf16x8*)(sA + (wr * 32 + t * 16 + l16) * 72 + kk + quad * 8);
#pragma unroll
      for (int t = 0; t < 4; t++)
        bfr[t] = *(const bf16x8*)(sW + (wc * 64 + t * 16 + l16) * 72 + kk + quad * 8);
#pragma unroll
      for (int i = 0; i < 2; i++)
#pragma unroll
        for (int j = 0; j < 4; j++)
          acc[i][j] = __builtin_amdgcn_mfma_f32_16x16x32_bf16(af[i], bfr[j], acc[i][j], 0, 0, 0);
    }
    __syncthreads();
  }

  // epilogue: +b_from, scatter to out1 (all listed rows are masked; no blend)
#pragma unroll
  for (int i = 0; i < 2; i++) {
#pragma unroll
    for (int e = 0; e < 4; e++) {
      int row = wr * 32 + i * 16 + quad * 4 + e;
      int sr = sIdx[row];
      if (sr >= 0) {
        size_t gr = rbase + sr;
#pragma unroll
        for (int j = 0; j < 4; j++) {
          int col = nc0 + wc * 64 + j * 16 + l16;
          out1[gr * H + col] = acc[i][j][e] + b_from[col];
        }
      }
    }
  }
}

extern "C" void kernel_launch(void* const* d_in, const int* in_sizes, int n_in,
                              void* d_out, int out_size, void* d_ws, size_t ws_size,
                              hipStream_t stream) {
  const float* hid    = (const float*)d_in[0];
  const float* W_to   = (const float*)d_in[1];
  const float* b_to   = (const float*)d_in[2];
  const float* W_from = (const float*)d_in[3];
  const float* b_from = (const float*)d_in[4];
  const int*   tok    = (const int*)d_in[5];
  const int*   tt     = (const int*)d_in[6];

  // workspace: wtT bf16 (P*H) | wfT bf16 (H*P) | maskf (S f32) | slist (S i32) | cnt
  ushort* wtT = (ushort*)d_ws;
  ushort* wfT = wtT + (size_t)P * H;
  float* maskf = (float*)(wfT + (size_t)H * P);
  int* slist = (int*)(maskf + S);
  int* cntp = slist + S;

  float* out0 = (float*)d_out;                    // private_reasoning (B,S,P)
  float* out1 = out0 + (size_t)BB * S * P;        // output (B,S,H)
  float* out2 = out1 + (size_t)BB * S * H;        // is_private (B,S)
  float* out3 = out2 + (size_t)BB * S;            // subspace_usage (B)

  hipLaunchKernelGGL(prep, dim3(1025), dim3(256), 0, stream,
                     W_to, W_from, wtT, wfT, tok, tt, maskf, slist, cntp, out2, out3);
  hipLaunchKernelGGL(gemm1, dim3(M_TOTAL / 64), dim3(512), 0, stream,
                     hid, wtT, b_to, maskf, out0, out1);
  hipLaunchKernelGGL(gemm2, dim3((M_TOTAL / 128) * (H / 128)), dim3(512), 0, stream,
                     out0, wfT, b_from, slist, cntp, out1);
}

// Round 4
// 603.477 us; speedup vs baseline: 1.2765x; 1.0019x over previous
//
#include <hip/hip_runtime.h>
#include <stdint.h>

// InnerMonologue: PR = hid @ W_to + b_to ; proj = PR @ W_from + b_from
// out = mask ? proj : hid ; mask = parity of cumulative thought-token count (row 0).
// Outputs concat: PR (B,S,P) | out (B,S,H) | is_private (B,S) | usage (B), all fp32.
//
// R4: W tiles staged via __builtin_amdgcn_global_load_lds (width 16) in both
// GEMMs. Linear LDS W layout (stride 64 ushorts) + inverse-swizzled per-lane
// global source + XOR-swizzled ds_read (rule #21 pattern): conflict level stays
// 2-way (free), staging loses the VGPR round-trip. Rest identical to R3.

#define H 2048
#define P 256
#define BB 4
#define S 8192
#define M_TOTAL (BB * S)

typedef __bf16 bf16x8 __attribute__((ext_vector_type(8)));
typedef float f32x4 __attribute__((ext_vector_type(4)));

typedef const __attribute__((address_space(1))) uint32_t* gas_ptr;
typedef __attribute__((address_space(3))) uint32_t* las_ptr;

__device__ __forceinline__ void gload16(const ushort* g, ushort* l) {
  // async global->LDS DMA, 16B per lane; LDS dest = wave-uniform base + lane*16
  __builtin_amdgcn_global_load_lds((gas_ptr)g, (las_ptr)l, 16, 0, 0);
}

__device__ __forceinline__ ushort f2b(float f) {
  // fp32 -> bf16 round-to-nearest-even
  uint32_t u = __float_as_uint(f);
  u += 0x7fffu + ((u >> 16) & 1u);
  return (ushort)(u >> 16);
}

// ---------------- prep: weight transposes + mask + masked-row compaction ----------------
// blocks 0..511: W_to (H x P) -> wtT (P x H) ; 512..1023: W_from -> wfT ;
// block 1024: mask / is_private / usage / sorted masked-position list.
__global__ __launch_bounds__(256) void prep(
    const float* __restrict__ W_to, const float* __restrict__ W_from,
    ushort* __restrict__ wtT, ushort* __restrict__ wfT,
    const int* __restrict__ tok, const int* __restrict__ tt_p,
    float* __restrict__ maskf, int* __restrict__ slist, int* __restrict__ cntp,
    float* __restrict__ out2, float* __restrict__ out3) {
  __shared__ float tile[32][33];
  __shared__ unsigned long long wpar[4];
  __shared__ int scnt[256];
  const int b = blockIdx.x;
  const int t = threadIdx.x;
  if (b < 1024) {
    const float* in = (b < 512) ? W_to : W_from;
    ushort* out = (b < 512) ? wtT : wfT;
    const int R = (b < 512) ? H : P;
    const int C = (b < 512) ? P : H;
    const int bb = b & 511;
    const int nct = C >> 5;
    const int c0 = (bb % nct) * 32, r0 = (bb / nct) * 32;
    const int tx = t & 31, ty = t >> 5;  // 32 x 8
#pragma unroll
    for (int j = 0; j < 32; j += 8)
      tile[ty + j][tx] = in[(size_t)(r0 + ty + j) * C + c0 + tx];
    __syncthreads();
#pragma unroll
    for (int j = 0; j < 32; j += 8)
      out[(size_t)(c0 + ty + j) * R + r0 + tx] = f2b(tile[tx][ty + j]);
  } else {
    const int lane = t & 63, w = t >> 6;
    const int tt = tt_p[0];
    const int base = t * 32;
    unsigned bits = 0;
    for (int i = 0; i < 32; i++) bits |= (unsigned)(tok[base + i] == tt) << i;
    const int par = __popc(bits) & 1;
    const unsigned long long bal = __ballot(par != 0);
    if (lane == 0) wpar[w] = bal;
    __syncthreads();
    int pre = 0;
    for (int j = 0; j < w; j++) pre ^= (int)(__popcll(wpar[j]) & 1);
    pre ^= (int)(__popcll(bal & ((1ull << lane) - 1ull)) & 1);
    int cnt = 0;
    for (int i = 0; i < 32; i++) {
      int inc = __popc(bits << (31 - i)) & 1;  // inclusive parity of bits[0..i]
      cnt += pre ^ inc;
    }
    scnt[t] = cnt;
    __syncthreads();
    int off = 0, tot = 0;
    for (int j = 0; j < 256; j++) {
      if (j < t) off += scnt[j];
      tot += scnt[j];
    }
    for (int i = 0; i < 32; i++) {
      int inc = __popc(bits << (31 - i)) & 1;
      int bit = pre ^ inc;
      float fb = (float)bit;
      maskf[base + i] = fb;
      out2[0 * S + base + i] = fb;
      out2[1 * S + base + i] = fb;
      out2[2 * S + base + i] = fb;
      out2[3 * S + base + i] = fb;
      if (bit) slist[off++] = base + i;
    }
    const int padded = (tot + 127) & ~127;
    for (int idx = tot + t; idx < padded; idx += 256) slist[idx] = -1;
    if (t == 0) cntp[0] = tot;
    if (t < BB) out3[t] = (float)tot / (float)S;
  }
}

// ---------------- GEMM1: PR(64x256 per block) = hid @ W_to + b_to ----------------
// grid 512 x 512 threads. LDS = 64x72 + 256x64 ushort = 41KB -> 3 blocks/CU.
// 8 waves each own 64 rows x 32 cols (acc[4][2]). W via global_load_lds.
// Passthrough: unmasked rows' hid float4 (already in staging regs) -> out1.
__global__ __launch_bounds__(512) void gemm1(
    const float* __restrict__ hid,
    const ushort* __restrict__ wtT,   // P x H bf16  (W_to^T)
    const float* __restrict__ b_to,
    const float* __restrict__ maskf,
    float* __restrict__ out0,         // (B*S, P) fp32
    float* __restrict__ out1)         // (B*S, H) fp32
{
  __shared__ __align__(16) ushort sA[64 * 72];
  __shared__ __align__(16) ushort sW[256 * 64];  // linear rows, XOR-swizzled content
  const int tid = threadIdx.x;
  const int lane = tid & 63, wid = tid >> 6;
  const int quad = lane >> 4, l16 = lane & 15;
  const int swz = (l16 & 7) << 3;   // read-side XOR (ushort units)
  const int row0 = blockIdx.x * 64;

  // W gload geometry: wave wid stages 4 groups of 8 rows (rows wid*32 + 8j + grow).
  // Lane l reads its row's 16B chunk at k-offset kx so the linear LDS burst lands
  // XOR-swizzled: content at (row, byte) = W^T[row][byte ^ ((row&7)<<4)].
  const int grow = lane >> 3;                      // 0..7
  const int kx = (((lane & 7) ^ (grow & 7)) << 3); // 0..56 (ushort units)
  const ushort* wSrcBase = wtT + (size_t)(wid * 32 + grow) * H + kx;
  ushort* wDstBase = sW + wid * 4 * 512;           // 4 groups x 8 rows x 64

  // A staging geometry: thread handles rows ra and ra+32, float4 chunk cc
  const int ra = tid >> 4, cc = tid & 15;
  const bool pass0 = (maskf[(row0 + ra) & (S - 1)] == 0.0f);
  const bool pass1 = (maskf[(row0 + 32 + ra) & (S - 1)] == 0.0f);
  const float* aSrc0 = hid + (size_t)(row0 + ra) * H + cc * 4;
  const float* aSrc1 = hid + (size_t)(row0 + 32 + ra) * H + cc * 4;
  float* pDst0 = out1 + (size_t)(row0 + ra) * H + cc * 4;
  float* pDst1 = out1 + (size_t)(row0 + 32 + ra) * H + cc * 4;

  f32x4 acc[4][2];
  const f32x4 zero = {0.f, 0.f, 0.f, 0.f};
#pragma unroll
  for (int i = 0; i < 4; i++)
#pragma unroll
    for (int j = 0; j < 2; j++) acc[i][j] = zero;

  for (int k0 = 0; k0 < H; k0 += 64) {
    // stage W: 4 async DMA bursts per wave (issue first, overlap with A VALU work)
#pragma unroll
    for (int j = 0; j < 4; j++)
      gload16(wSrcBase + (size_t)(8 * j) * H + k0, wDstBase + j * 512);
    // stage A: 64 rows x 64 k, fp32 -> bf16 ; passthrough unmasked rows to out1
    {
      const float4 v0 = *(const float4*)(aSrc0 + k0);
      ushort4 b0;
      b0.x = f2b(v0.x); b0.y = f2b(v0.y); b0.z = f2b(v0.z); b0.w = f2b(v0.w);
      *(ushort4*)(sA + ra * 72 + cc * 4) = b0;
      if (pass0) *(float4*)(pDst0 + k0) = v0;
      const float4 v1 = *(const float4*)(aSrc1 + k0);
      ushort4 b1;
      b1.x = f2b(v1.x); b1.y = f2b(v1.y); b1.z = f2b(v1.z); b1.w = f2b(v1.w);
      *(ushort4*)(sA + (32 + ra) * 72 + cc * 4) = b1;
      if (pass1) *(float4*)(pDst1 + k0) = v1;
    }
    __syncthreads();
#pragma unroll
    for (int kk = 0; kk < 64; kk += 32) {
      bf16x8 af[4], bfr[2];
#pragma unroll
      for (int t = 0; t < 4; t++)
        af[t] = *(const bf16x8*)(sA + (t * 16 + l16) * 72 + kk + quad * 8);
#pragma unroll
      for (int t = 0; t < 2; t++)
        bfr[t] = *(const bf16x8*)(sW + (wid * 32 + t * 16 + l16) * 64 + ((kk + quad * 8) ^ swz));
#pragma unroll
      for (int i = 0; i < 4; i++)
#pragma unroll
        for (int j = 0; j < 2; j++)
          acc[i][j] = __builtin_amdgcn_mfma_f32_16x16x32_bf16(af[i], bfr[j], acc[i][j], 0, 0, 0);
    }
    __syncthreads();
  }

  // epilogue: +b_to, write PR fp32 (all rows)
#pragma unroll
  for (int i = 0; i < 4; i++) {
#pragma unroll
    for (int j = 0; j < 2; j++) {
      int col = wid * 32 + j * 16 + l16;
      float bias = b_to[col];
#pragma unroll
      for (int e = 0; e < 4; e++) {
        int row = i * 16 + quad * 4 + e;
        out0[(size_t)(row0 + row) * P + col] = acc[i][j][e] + bias;
      }
    }
  }
}

// ---------------- GEMM2: masked rows only ----------------
// out1[masked] = PR[masked] @ W_from + b_from. 128 gathered rows x 128 cols per
// block; grid 4096, blocks beyond the active tile count exit immediately.
// W via global_load_lds (same swizzle pattern). slist sorted -> coalescing kept.
__global__ __launch_bounds__(512) void gemm2(
    const float* __restrict__ pr,     // out0: (B*S, P) fp32
    const ushort* __restrict__ wfT,   // H x P bf16  (W_from^T)
    const float* __restrict__ b_from,
    const int* __restrict__ slist,
    const int* __restrict__ cntp,
    float* __restrict__ out1)         // (B*S, H) fp32
{
  __shared__ __align__(16) ushort sA[128 * 72];
  __shared__ __align__(16) ushort sW[128 * 64];  // linear rows, swizzled content
  __shared__ int sIdx[128];
  const int tid = threadIdx.x;

  const int cnt = cntp[0];
  const int tpb = (cnt + 127) >> 7;   // m-tiles per batch
  const int u0 = ((blockIdx.x & 7) << 9) + (blockIdx.x >> 3);  // bijective XCD swizzle
  const int mt = u0 >> 4;
  if (mt >= 4 * tpb) return;
  const int nt = u0 & 15;
  const int batch = mt / tpb, ms = mt - batch * tpb;
  const int nc0 = nt * 128;
  const size_t rbase = (size_t)batch * S;

  if (tid < 128) sIdx[tid] = slist[ms * 128 + tid];
  __syncthreads();

  const int lane = tid & 63, wid = tid >> 6;
  const int quad = lane >> 4, l16 = lane & 15;
  const int swz = (l16 & 7) << 3;
  const int wr = wid >> 1, wc = wid & 1;

  // W gload geometry: wave wid stages 2 groups of 8 rows (rows nc0 + wid*16 + 8j + grow)
  const int grow = lane >> 3;
  const int kx = (((lane & 7) ^ (grow & 7)) << 3);
  const ushort* wSrcBase = wfT + (size_t)(nc0 + wid * 16 + grow) * P + kx;
  ushort* wDstBase = sW + wid * 2 * 512;

  // A staging geometry: thread handles tile rows ra + p*32, float4 chunk cc
  const int ra = tid >> 4, cc = tid & 15;
  const float* aSrc[4];
#pragma unroll
  for (int p = 0; p < 4; p++) {
    int sr = sIdx[ra + p * 32];
    int s = (sr < 0) ? 0 : sr;        // sentinel rows load row 0 (never stored)
    aSrc[p] = pr + (rbase + s) * P + cc * 4;
  }

  f32x4 acc[2][4];
  const f32x4 zero = {0.f, 0.f, 0.f, 0.f};
#pragma unroll
  for (int i = 0; i < 2; i++)
#pragma unroll
    for (int j = 0; j < 4; j++) acc[i][j] = zero;

  for (int k0 = 0; k0 < P; k0 += 64) {
    // stage W: 2 async DMA bursts per wave
#pragma unroll
    for (int j = 0; j < 2; j++)
      gload16(wSrcBase + (size_t)(8 * j) * P + k0, wDstBase + j * 512);
    // stage A: 128 gathered rows x 64 k from PR fp32 -> bf16
#pragma unroll
    for (int p = 0; p < 4; p++) {
      const float4 v = *(const float4*)(aSrc[p] + k0);
      ushort4 b;
      b.x = f2b(v.x); b.y = f2b(v.y); b.z = f2b(v.z); b.w = f2b(v.w);
      *(ushort4*)(sA + (p * 32 + ra) * 72 + cc * 4) = b;
    }
    __syncthreads();
#pragma unroll
    for (int kk = 0; kk < 64; kk += 32) {
      bf16x8 af[2], bfr[4];
#pragma unroll
      for (int t = 0; t < 2; t++)
        af[t] = *(const bf16x8*)(sA + (wr * 32 + t * 16 + l16) * 72 + kk + quad * 8);
#pragma unroll
      for (int t = 0; t < 4; t++)
        bfr[t] = *(const bf16x8*)(sW + (wc * 64 + t * 16 + l16) * 64 + ((kk + quad * 8) ^ swz));
#pragma unroll
      for (int i = 0; i < 2; i++)
#pragma unroll
        for (int j = 0; j < 4; j++)
          acc[i][j] = __builtin_amdgcn_mfma_f32_16x16x32_bf16(af[i], bfr[j], acc[i][j], 0, 0, 0);
    }
    __syncthreads();
  }

  // epilogue: +b_from, scatter to out1 (all listed rows are masked; no blend)
#pragma unroll
  for (int i = 0; i < 2; i++) {
#pragma unroll
    for (int e = 0; e < 4; e++) {
      int row = wr * 32 + i * 16 + quad * 4 + e;
      int sr = sIdx[row];
      if (sr >= 0) {
        size_t gr = rbase + sr;
#pragma unroll
        for (int j = 0; j < 4; j++) {
          int col = nc0 + wc * 64 + j * 16 + l16;
          out1[gr * H + col] = acc[i][j][e] + b_from[col];
        }
      }
    }
  }
}

extern "C" void kernel_launch(void* const* d_in, const int* in_sizes, int n_in,
                              void* d_out, int out_size, void* d_ws, size_t ws_size,
                              hipStream_t stream) {
  const float* hid    = (const float*)d_in[0];
  const float* W_to   = (const float*)d_in[1];
  const float* b_to   = (const float*)d_in[2];
  const float* W_from = (const float*)d_in[3];
  const float* b_from = (const float*)d_in[4];
  const int*   tok    = (const int*)d_in[5];
  const int*   tt     = (const int*)d_in[6];

  // workspace: wtT bf16 (P*H) | wfT bf16 (H*P) | maskf (S f32) | slist (S i32) | cnt
  ushort* wtT = (ushort*)d_ws;
  ushort* wfT = wtT + (size_t)P * H;
  float* maskf = (float*)(wfT + (size_t)H * P);
  int* slist = (int*)(maskf + S);
  int* cntp = slist + S;

  float* out0 = (float*)d_out;                    // private_reasoning (B,S,P)
  float* out1 = out0 + (size_t)BB * S * P;        // output (B,S,H)
  float* out2 = out1 + (size_t)BB * S * H;        // is_private (B,S)
  float* out3 = out2 + (size_t)BB * S;            // subspace_usage (B)

  hipLaunchKernelGGL(prep, dim3(1025), dim3(256), 0, stream,
                     W_to, W_from, wtT, wfT, tok, tt, maskf, slist, cntp, out2, out3);
  hipLaunchKernelGGL(gemm1, dim3(M_TOTAL / 64), dim3(512), 0, stream,
                     hid, wtT, b_to, maskf, out0, out1);
  hipLaunchKernelGGL(gemm2, dim3((M_TOTAL / 128) * (H / 128)), dim3(512), 0, stream,
                     out0, wfT, b_from, slist, cntp, out1);
}